// Round 1
// 361.343 us; speedup vs baseline: 1.0042x; 1.0042x over previous
//
#include <hip/hip_runtime.h>
#include <hip/hip_bf16.h>

// Shapes (fixed by the reference)
#define QN 64
#define SQ 32
#define CN 256
#define SC 256
#define HD 768
#define DD 128

typedef __attribute__((ext_vector_type(8))) short short8;   // 8 bf16 = 4 VGPR
typedef __attribute__((ext_vector_type(4))) float f32x4;    // MFMA acc

// ---- bf16 pack helpers (RNE) ----
static __device__ __forceinline__ unsigned short f2bf(float x) {
  unsigned u = __float_as_uint(x);
  unsigned r = 0x7FFFu + ((u >> 16) & 1u);
  return (unsigned short)((u + r) >> 16);
}
static __device__ __forceinline__ unsigned pack2(float a, float b) {
  return (unsigned)f2bf(a) | ((unsigned)f2bf(b) << 16);
}

// ---- async global->LDS, 16B/lane; LDS dest = wave-uniform base + lane*16 ----
typedef const __attribute__((address_space(1))) unsigned int* as1_u32p;
typedef __attribute__((address_space(3))) unsigned int* as3_u32p;
static __device__ __forceinline__ void gl_lds16(const void* g, void* l) {
  __builtin_amdgcn_global_load_lds((as1_u32p)g, (as3_u32p)l, 16, 0, 0);
}

// ---------------------------------------------------------------------------
// Prep (fused):
//  blocks [0,128):  WtS[d][kc'] = bf16(W[k][d]) in 16B chunks (8 bf16), XOR
//                   swizzled within 8-chunk groups: kc' = (kc&~7)|((kc&7)^(d&7)).
//  blocks [128,448): pooled l2norm rows (64 q + 256 c); q rows also zero
//                   qcolP pad row 31.
// ---------------------------------------------------------------------------
__global__ __launch_bounds__(256) void prep_kernel(
    const float* __restrict__ W,
    const float* __restrict__ qh, const int* __restrict__ qm,
    const float* __restrict__ ch, const int* __restrict__ cm,
    unsigned short* __restrict__ WtS,
    float* __restrict__ outq, float* __restrict__ outc,
    unsigned short* __restrict__ qcolP) {
  __shared__ float red[4];
  int bid = blockIdx.x, tid = threadIdx.x;

  if (bid < DD) {  // W transpose-convert, swizzled chunks
    int d = bid;
    if (tid < 96) {
      int kc = tid;
      unsigned p[4];
#pragma unroll
      for (int e = 0; e < 4; ++e) {
        float a = W[(size_t)(kc * 8 + 2 * e) * DD + d];
        float b = W[(size_t)(kc * 8 + 2 * e + 1) * DD + d];
        p[e] = pack2(a, b);
      }
      int kcp = (kc & ~7) | ((kc & 7) ^ (d & 7));
      *(uint4*)&WtS[((size_t)d * 96 + kcp) * 8] = *(uint4*)p;
    }
    return;
  }

  int row = bid - DD;
  const float* src;
  float* dst;
  float m;
  if (row < QN) {
    src = qh + (size_t)row * SQ * HD;
    m = (float)qm[row * SQ];
    dst = outq + (size_t)row * HD;
  } else {
    int b = row - QN;
    src = ch + (size_t)b * SC * HD;
    m = (float)cm[b * SC];
    dst = outc + (size_t)b * HD;
  }
  float ss = 0.f;
  for (int k = tid; k < HD; k += 256) {
    float v = src[k] * m;
    ss += v * v;
  }
  int lane = tid & 63, wv = tid >> 6;
  for (int off = 32; off; off >>= 1) ss += __shfl_xor(ss, off);
  if (lane == 0) red[wv] = ss;
  __syncthreads();
  float tot = red[0] + red[1] + red[2] + red[3];
  float inv = 1.f / fmaxf(sqrtf(tot), 1e-12f);
  for (int k = tid; k < HD; k += 256) dst[k] = src[k] * m * inv;
  if (row < QN && tid < 64)
    ((unsigned*)(qcolP + ((size_t)row * 32 + 31) * DD))[tid] = 0u;
}

// ---------------------------------------------------------------------------
// Projection GEMM (MFMA): col = l2norm(m*(h@W) + b)
//  M=64 tile, BK=64, 12 k-steps. Blocks [0,1020): c tokens. [1020,1051): q.
//  2-phase double-buffered pipeline: stage(step+1) into buf^1 BEFORE compute
//  of buf (T3-minimum, guide §5.5) — one __syncthreads per step, loads always
//  in flight. LDS: 2*(16KB A + 16KB W) = 64 KB -> 2 blocks/CU.
//  A's LDS image is chunk-XOR-swizzled via the GLOBAL source address (linear
//  dest constraint of global_load_lds); W source (WtS) is pre-swizzled.
//  Mask applied in epilogue (exact: (h*m)@W + b == m*(h@W) + b).
// ---------------------------------------------------------------------------
union ProjLDS {
  struct { float a[2][64 * 64]; unsigned short w[2][128 * 64]; } s;  // 32+32 KB
  float cep[64 * 132];                                               // 33.8 KB
};

__global__ __launch_bounds__(256, 2) void proj_kernel(
    const float* __restrict__ q_hidden, const float* __restrict__ c_hidden,
    const int* __restrict__ q_mask, const int* __restrict__ c_mask,
    const unsigned short* __restrict__ WtS, const float* __restrict__ bias,
    unsigned short* __restrict__ qcol, unsigned short* __restrict__ ccol) {
  __shared__ ProjLDS u;
  int bx = blockIdx.x;
  int isQ = (bx >= 1020) ? 1 : 0;
  int base = isQ ? (bx - 1020) : bx;
  int tid = threadIdx.x, lane = tid & 63, wv = tid >> 6;
  int lm = lane & 15, lq = lane >> 4;

  // ---- A staging sources: 4 slots/thread, slot = i*256+tid ----
  // row r = i*16 + (tid>>4); phys chunk p = tid&15; logical c = (p&8)|((p&7)^(r&7))
  int ac = (tid & 8) | ((tid & 7) ^ ((tid >> 4) & 7));
  const float* aptr[4];
#pragma unroll
  for (int i = 0; i < 4; ++i) {
    int r = i * 16 + (tid >> 4);
    int g = base * 64 + r;
    const float* hp;
    if (isQ) {  // 31 blocks * 64 = 1984 rows exactly: no clamp needed
      int qq = g / 31, t = g - qq * 31;
      hp = q_hidden + ((size_t)qq * SQ + t + 1) * HD;
    } else {    // 1020 blocks * 64 = 65280 rows exactly
      int cb = g / 255, t = g - cb * 255;
      hp = c_hidden + ((size_t)cb * SC + t + 1) * HD;
    }
    aptr[i] = hp + ac * 4;
  }
  // ---- W staging sources: 4 slots/thread (linear copy of pre-swizzled WtS) ----
  const unsigned short* wptr[4];
#pragma unroll
  for (int i = 0; i < 4; ++i) {
    int d = i * 32 + (tid >> 3);
    wptr[i] = WtS + ((size_t)d * 96 + (tid & 7)) * 8;
  }

  f32x4 acc[8];
#pragma unroll
  for (int j = 0; j < 8; ++j) acc[j] = (f32x4){0.f, 0.f, 0.f, 0.f};

  // ---- prologue: stage step 0 into buffer 0 ----
#pragma unroll
  for (int i = 0; i < 4; ++i)
    gl_lds16(aptr[i], (char*)&u.s.a[0][0] + (size_t)(i * 256 + wv * 64) * 16);
#pragma unroll
  for (int i = 0; i < 4; ++i)
    gl_lds16(wptr[i], (char*)&u.s.w[0][0] + (size_t)(i * 256 + wv * 64) * 16);
  __syncthreads();

  for (int step = 0; step < 12; ++step) {
    int cur = step & 1;
    if (step < 11) {  // issue next-step loads BEFORE compute (2-phase)
      int nxt = cur ^ 1;
#pragma unroll
      for (int i = 0; i < 4; ++i)
        gl_lds16(aptr[i] + (step + 1) * 64,
                 (char*)&u.s.a[nxt][0] + (size_t)(i * 256 + wv * 64) * 16);
#pragma unroll
      for (int i = 0; i < 4; ++i)
        gl_lds16(wptr[i] + (step + 1) * 64,
                 (char*)&u.s.w[nxt][0] + (size_t)(i * 256 + wv * 64) * 16);
    }
#pragma unroll
    for (int w = 0; w < 2; ++w) {  // 2 k-windows of 32 per step
      int rr = wv * 16 + lm;
      int x0 = (lq * 2) ^ (lm & 7);
      int x1 = (lq * 2 + 1) ^ (lm & 7);
      float4 a0 = *(const float4*)&u.s.a[cur][rr * 64 + w * 32 + x0 * 4];
      float4 a1 = *(const float4*)&u.s.a[cur][rr * 64 + w * 32 + x1 * 4];
      unsigned p[4];
      p[0] = pack2(a0.x, a0.y); p[1] = pack2(a0.z, a0.w);
      p[2] = pack2(a1.x, a1.y); p[3] = pack2(a1.z, a1.w);
      short8 afr = *(short8*)p;
#pragma unroll
      for (int nt = 0; nt < 8; ++nt) {
        int d = nt * 16 + lm;
        int pc = (w * 4 + lq) ^ (lm & 7);
        short8 bfr = *(const short8*)&u.s.w[cur][d * 64 + pc * 8];
        acc[nt] = __builtin_amdgcn_mfma_f32_16x16x32_bf16(afr, bfr, acc[nt], 0, 0, 0);
      }
    }
    __syncthreads();  // drains next-step loads (overlapped with compute above)
  }

  // ---- epilogue: single 64-row pass through LDS (reuses staging space) ----
#pragma unroll
  for (int nt = 0; nt < 8; ++nt)
#pragma unroll
    for (int r = 0; r < 4; ++r) {
      int row = wv * 16 + lq * 4 + r;
      u.cep[row * 132 + nt * 16 + lm] = acc[nt][r];
    }
  __syncthreads();

  int tk = tid >> 2, qt = tid & 3;  // row, 32-d quarter
  int g = base * 64 + tk;
  int qq, t;
  float fm;
  if (isQ) {
    qq = g / 31; t = g - qq * 31;
    fm = (float)q_mask[qq * SQ + t + 1];
  } else {
    qq = g / 255; t = g - qq * 255;
    fm = (float)c_mask[qq * SC + t + 1];
  }

  float v[32];
  float ss = 0.f;
#pragma unroll
  for (int j = 0; j < 8; ++j) {
    float4 cv = *(const float4*)&u.cep[tk * 132 + qt * 32 + j * 4];
    float4 bv = *(const float4*)&bias[qt * 32 + j * 4];
    v[4 * j + 0] = cv.x * fm + bv.x; v[4 * j + 1] = cv.y * fm + bv.y;
    v[4 * j + 2] = cv.z * fm + bv.z; v[4 * j + 3] = cv.w * fm + bv.w;
#pragma unroll
    for (int e = 0; e < 4; ++e) ss += v[4 * j + e] * v[4 * j + e];
  }
  ss += __shfl_xor(ss, 1);
  ss += __shfl_xor(ss, 2);
  float inv = 1.f / fmaxf(sqrtf(ss), 1e-12f);

  uint4 pk4[4];
#pragma unroll
  for (int j = 0; j < 4; ++j) {
    unsigned p[4];
#pragma unroll
    for (int e = 0; e < 4; ++e)
      p[e] = pack2(v[8 * j + 2 * e] * inv, v[8 * j + 2 * e + 1] * inv);
    pk4[j] = *(uint4*)p;
  }

  if (isQ) {
    uint4* dst = (uint4*)(qcol + ((size_t)qq * 32 + t) * DD + qt * 32);
#pragma unroll
    for (int j = 0; j < 4; ++j) dst[j] = pk4[j];
  } else {
    uint4* rowp = (uint4*)(ccol + ((size_t)qq * 256 + t) * DD);
#pragma unroll
    for (int j = 0; j < 4; ++j) {
      int kc = qt * 4 + j;
      int p = (kc & 8) | ((kc & 7) ^ (t & 7));
      rowp[p] = pk4[j];
    }
    if (t == 254) {  // duplicate into pad row 255 (row&7 = 7); next row = +16 uint4
      uint4* rowp2 = rowp + 16;
#pragma unroll
      for (int j = 0; j < 4; ++j) {
        int kc = qt * 4 + j;
        int p = (kc & 8) | ((kc & 7) ^ 7);
        rowp2[p] = pk4[j];
      }
    }
  }
}

// ---------------------------------------------------------------------------
// Sim (MFMA): sim[q,c] = (sum_i max_j qcol[q,i]·ccol[c,j]) / denom[q]
// Grid (128, 4), 256 thr = 4 waves, 2 blocks/CU. 4 q per wave (16 q/block),
// 2 c-docs per block processed as 4 half-tiles (128 c-rows = 32 KB each),
// double-buffered: stage(half+1) issued before compute(half) — one barrier
// per half. ccol is pre-swizzled by proj; frag reads use the same XOR.
// ---------------------------------------------------------------------------
__global__ __launch_bounds__(256, 2) void sim_kernel(
    const unsigned short* __restrict__ qcolP,  // [64][32][128], row 31 zero
    const unsigned short* __restrict__ ccol,   // swizzled, row 255 dup
    const int* __restrict__ qmask,
    float* __restrict__ sim) {
  __shared__ unsigned short cbuf[2][128 * 128];  // 2 x 32 KB
  int tid = threadIdx.x, lane = tid & 63, wv = tid >> 6;
  int lm = lane & 15, lq = lane >> 4;
  int qb = blockIdx.y * 16 + wv * 4;  // 4 q per wave
  int c0 = blockIdx.x * 2;

  // B fragments (q side): af[q2][it][kf]
  short8 af[4][2][4];
#pragma unroll
  for (int q2 = 0; q2 < 4; ++q2)
#pragma unroll
    for (int it = 0; it < 2; ++it)
#pragma unroll
      for (int kf = 0; kf < 4; ++kf)
        af[q2][it][kf] = *(const short8*)(qcolP +
            (((size_t)(qb + q2) * 32 + it * 16 + lm) * DD + kf * 32 + lq * 8));

  float dinv[4];
#pragma unroll
  for (int q2 = 0; q2 < 4; ++q2) {
    float v = (lane >= 1 && lane < 32) ? (float)qmask[(qb + q2) * SQ + lane] : 0.f;
    for (int off = 1; off < 64; off <<= 1) v += __shfl_xor(v, off);
    dinv[q2] = 1.f / v;
  }

  const unsigned short* csrc = ccol + (size_t)c0 * SC * DD;  // 4 contiguous halves

  // prologue: stage half 0 into buffer 0
#pragma unroll
  for (int i = 0; i < 8; ++i)
    gl_lds16(csrc + (size_t)(i * 256 + tid) * 8,
             (char*)&cbuf[0][0] + (size_t)(i * 256 + wv * 64) * 16);
  __syncthreads();

  float rmax[4][2];
  for (int ht = 0; ht < 4; ++ht) {  // 2 c-docs x 2 halves
    int b = ht & 1;
    if (!(ht & 1)) {
#pragma unroll
      for (int q2 = 0; q2 < 4; ++q2) {
        rmax[q2][0] = -__builtin_inff();
        rmax[q2][1] = -__builtin_inff();
      }
    }
    if (ht < 3) {  // prefetch next half into other buffer (2-phase)
      const unsigned short* s2 = csrc + (size_t)(ht + 1) * 16384;
#pragma unroll
      for (int i = 0; i < 8; ++i)
        gl_lds16(s2 + (size_t)(i * 256 + tid) * 8,
                 (char*)&cbuf[b ^ 1][0] + (size_t)(i * 256 + wv * 64) * 16);
    }

    for (int jt = 0; jt < 8; ++jt) {
      short8 cf[4];  // A operand: c rows jt*16+lm of this half
#pragma unroll
      for (int kf = 0; kf < 4; ++kf) {
        int row = jt * 16 + lm;
        int kc = kf * 4 + lq;
        int p = (kc & 8) | ((kc & 7) ^ (row & 7));
        cf[kf] = *(const short8*)&cbuf[b][(size_t)(row * 16 + p) * 8];
      }
#pragma unroll
      for (int q2 = 0; q2 < 4; ++q2)
#pragma unroll
        for (int it = 0; it < 2; ++it) {
          f32x4 acc = (f32x4){0.f, 0.f, 0.f, 0.f};
#pragma unroll
          for (int kf = 0; kf < 4; ++kf)
            acc = __builtin_amdgcn_mfma_f32_16x16x32_bf16(cf[kf], af[q2][it][kf], acc, 0, 0, 0);
          float loc = fmaxf(fmaxf(acc[0], acc[1]), fmaxf(acc[2], acc[3]));
          rmax[q2][it] = fmaxf(rmax[q2][it], loc);
        }
    }

    if (ht & 1) {  // finalize doc c = c0 + (ht>>1)
      int c = c0 + (ht >> 1);
#pragma unroll
      for (int q2 = 0; q2 < 4; ++q2) {
        float m0 = rmax[q2][0], m1 = rmax[q2][1];
        m0 = fmaxf(m0, __shfl_xor(m0, 16)); m0 = fmaxf(m0, __shfl_xor(m0, 32));
        m1 = fmaxf(m1, __shfl_xor(m1, 16)); m1 = fmaxf(m1, __shfl_xor(m1, 32));
        // q-row i = lm (+16 for it=1); pad row 31 = (it=1, lm=15) excluded
        float s = m0 + ((lm == 15) ? 0.f : m1);
        s += __shfl_xor(s, 1); s += __shfl_xor(s, 2);
        s += __shfl_xor(s, 4); s += __shfl_xor(s, 8);
        if (lane == 0) sim[(qb + q2) * CN + c] = s * dinv[q2];
      }
    }
    __syncthreads();  // buf[b] consumed by all waves; safe to restage next iter
  }
}

// ---------------------------------------------------------------------------
extern "C" void kernel_launch(void* const* d_in, const int* in_sizes, int n_in,
                              void* d_out, int out_size, void* d_ws, size_t ws_size,
                              hipStream_t stream) {
  const float* q_hidden = (const float*)d_in[0];
  const float* c_hidden = (const float*)d_in[1];
  const float* W = (const float*)d_in[2];
  const float* bias = (const float*)d_in[3];
  const int* q_mask = (const int*)d_in[4];
  const int* c_mask = (const int*)d_in[5];

  float* out = (float*)d_out;
  float* sim = out;                      // 64*256
  float* q_pooled = out + QN * CN;       // 64*768
  float* c_pooled = q_pooled + QN * HD;  // 256*768

  unsigned short* WtS   = (unsigned short*)d_ws;                        // 192 KB
  unsigned short* qcolP = (unsigned short*)((char*)d_ws + (256 << 10)); // 512 KB
  unsigned short* ccol  = (unsigned short*)((char*)d_ws + (1 << 20));   // 16 MB

  prep_kernel<<<DD + QN + CN, 256, 0, stream>>>(W, q_hidden, q_mask, c_hidden, c_mask,
                                                WtS, q_pooled, c_pooled, qcolP);
  proj_kernel<<<1051, 256, 0, stream>>>(q_hidden, c_hidden, q_mask, c_mask,
                                        WtS, bias, qcolP, ccol);
  sim_kernel<<<dim3(128, 4), 256, 0, stream>>>(qcolP, ccol, q_mask, sim);
}